// Round 3
// baseline (131.385 us; speedup 1.0000x reference)
//
#include <hip/hip_runtime.h>
#include <hip/hip_bf16.h>
#include <stdint.h>

#define NB 4
#define NQL 1024
#define NL 2048
#define NH 16
#define NKVH 4
#define ND 128
#define KVBLK 64
// (1/sqrt(128)) * log2(e): scores land in log2 domain, softmax uses exp2
#define QSCALE_LOG2E 0.1275174340213733f

typedef __bf16 bf16_t;
typedef __bf16 bf16x4 __attribute__((ext_vector_type(4)));
typedef __bf16 bf16x8 __attribute__((ext_vector_type(8)));
typedef float f32x4 __attribute__((ext_vector_type(4)));
typedef float f32x16 __attribute__((ext_vector_type(16)));
typedef uint32_t u32;
typedef unsigned short u16;

__device__ __forceinline__ void gload_lds16(const void* g, void* l) {
  __builtin_amdgcn_global_load_lds((const __attribute__((address_space(1))) void*)g,
                                   (__attribute__((address_space(3))) void*)l,
                                   16, 0, 0);
}

__device__ __forceinline__ u32 pack_bf16(float a, float b) {
  u32 ua = (u32)__builtin_bit_cast(u16, (bf16_t)a);
  u32 ub = (u32)__builtin_bit_cast(u16, (bf16_t)b);
  return ua | (ub << 16);
}

// ---------------------------------------------------------------------------
// Kernel 1: scatter new k/v into caches -> f32 outputs; also bf16 K copy to ws.
// ---------------------------------------------------------------------------
__global__ __launch_bounds__(256) void update_cache_kernel(
    const float* __restrict__ knew,
    const float* __restrict__ vnew,
    const float* __restrict__ cache_k,
    const float* __restrict__ cache_v,
    const int*   __restrict__ seq_lens,
    float* __restrict__ new_ck,
    float* __restrict__ new_cv,
    bf16_t* __restrict__ kb)
{
  const int n4 = NB * NKVH * NL * ND / 4;
  for (int i = blockIdx.x * blockDim.x + threadIdx.x; i < 2 * n4;
       i += gridDim.x * blockDim.x) {
    const int which = i >= n4;
    const int j   = which ? i - n4 : i;
    const int d4  = j & 31;
    const int l   = (j >> 5) & (NL - 1);
    const int kvh = (j >> 16) & (NKVH - 1);
    const int b   = j >> 18;
    const int s   = seq_lens[b];
    float4 val;
    if (l >= s && l < s + NQL) {
      const float* nsrc = which ? vnew : knew;
      val = *(const float4*)(nsrc + (((size_t)(b * NQL + (l - s))) * NKVH + kvh) * ND + d4 * 4);
    } else {
      const float* csrc = which ? cache_v : cache_k;
      val = *(const float4*)(csrc + (((size_t)(b * NKVH + kvh)) * NL + l) * ND + d4 * 4);
    }
    const size_t coff = (((size_t)(b * NKVH + kvh)) * NL + l) * ND + d4 * 4;
    float* dst = which ? new_cv : new_ck;
    *(float4*)(dst + coff) = val;
    if (!which) {
      bf16x4 kv;
      kv[0] = (bf16_t)val.x; kv[1] = (bf16_t)val.y;
      kv[2] = (bf16_t)val.z; kv[3] = (bf16_t)val.w;
      *(bf16x4*)(kb + coff) = kv;
    }
  }
}

// ---------------------------------------------------------------------------
// Kernel 2: build bf16 V^T [B][KVH][D][L] from updated f32 V cache.
// ---------------------------------------------------------------------------
__global__ __launch_bounds__(256) void transpose_v_kernel(
    const float* __restrict__ new_cv, bf16_t* __restrict__ vt)
{
  __shared__ float T[64][129];
  const int tid = threadIdx.x;
  const int bid = blockIdx.x;        // B*KVH*(NL/64) = 512
  const int lt  = bid & 31;
  const int kvh = (bid >> 5) & (NKVH - 1);
  const int b   = bid >> 7;
  const int l0  = lt * 64;

  const float* src = new_cv + (((size_t)(b * NKVH + kvh)) * NL + l0) * ND;
  #pragma unroll
  for (int j = 0; j < 8; ++j) {
    const int i   = tid + j * 256;
    const int row = i >> 5, c4 = i & 31;
    float4 v = *(const float4*)(src + row * ND + c4 * 4);
    T[row][c4 * 4 + 0] = v.x; T[row][c4 * 4 + 1] = v.y;
    T[row][c4 * 4 + 2] = v.z; T[row][c4 * 4 + 3] = v.w;
  }
  __syncthreads();
  bf16_t* dst = vt + ((size_t)(b * NKVH + kvh)) * ND * NL;
  #pragma unroll
  for (int j = 0; j < 4; ++j) {
    const int c = tid + j * 256;
    const int d = c >> 3, l8 = c & 7;
    bf16x8 o;
    #pragma unroll
    for (int e = 0; e < 8; ++e) o[e] = (bf16_t)T[l8 * 8 + e][d];
    *(bf16x8*)(dst + (size_t)d * NL + l0 + l8 * 8) = o;
  }
}

// ---------------------------------------------------------------------------
// Kernel 3: flash attention. 512 blocks x 4 waves; wave owns 32 q-rows.
// s-rank complementary pairing: bid and bid+256 (same CU) get batches paired
// rank0<->rank3, rank1<->rank2 and q-tiles 2k<->7-2k, so per-CU work is
// ~constant regardless of the random seq_lens.
// ---------------------------------------------------------------------------
#define STAGE(buf, tt) do {                                                  \
    const int l0s = (tt) * KVBLK;                                            \
    _Pragma("unroll")                                                        \
    for (int j = 0; j < 4; ++j) {                                            \
      const int ck = tid + j * 256;                                          \
      const int kr = ck >> 4, kc2 = (ck & 15) ^ (kr & 7);                    \
      gload_lds16(kbb + (size_t)(l0s + kr) * ND + kc2 * 8,                   \
                  &Kl[buf][(wave * 64 + j * 256) * 8]);                      \
      const int vr = ck >> 3, vc2 = (ck & 7) ^ (vr & 7);                     \
      gload_lds16(vtb + (size_t)vr * NL + (l0s + vc2 * 8),                   \
                  &Vl[buf][(wave * 64 + j * 256) * 8]);                      \
    }                                                                        \
  } while (0)

__global__ __launch_bounds__(256, 2) void attn_kernel(
    const float* __restrict__ qin, const bf16_t* __restrict__ kb,
    const bf16_t* __restrict__ vt, const int* __restrict__ seq_lens,
    float* __restrict__ out)
{
  __shared__ bf16_t Kl[2][KVBLK * ND];   // 32 KB (XOR-swizzled rows of 256B)
  __shared__ bf16_t Vl[2][ND * KVBLK];   // 32 KB (XOR-swizzled rows of 128B)

  const int tid  = threadIdx.x;
  const int wave = tid >> 6, lane = tid & 63;
  const int l5   = lane & 31;            // q column within wave
  const int hi5  = lane >> 5;

  const int bid  = blockIdx.x;
  const int half = bid >> 8, r = bid & 255;
  // ---- s-rank pairing ----
  int sv[4];
  #pragma unroll
  for (int i = 0; i < 4; ++i) sv[i] = seq_lens[i];
  int rk[4];
  #pragma unroll
  for (int i = 0; i < 4; ++i) {
    int rr = 0;
    #pragma unroll
    for (int j = 0; j < 4; ++j)
      rr += (sv[j] > sv[i]) || (sv[j] == sv[i] && j < i);
    rk[rr] = i;
  }
  const int jb   = r >> 6;
  const int b    = half ? rk[3 - jb] : rk[jb];
  const int h    = (r >> 2) & (NH - 1);
  const int qt   = half ? (7 - ((r & 3) << 1)) : ((r & 3) << 1);
  const int kvh  = h >> 2;
  const int s    = sv[b];
  const int qw   = qt * 128 + wave * 32;
  const int q    = qw + l5;

  const bf16_t* kbb = kb + ((size_t)(b * NKVH + kvh)) * NL * ND;
  const bf16_t* vtb = vt + ((size_t)(b * NKVH + kvh)) * ND * NL;

  // Q fragments (B operand of S^T): qf[kc][j] = Q[q][kc*16 + hi5*8 + j]
  bf16x8 qf[8];
  {
    const float* qb = qin + ((size_t)((b * NQL + q) * NH + h)) * ND;
    #pragma unroll
    for (int kc = 0; kc < 8; ++kc) {
      float4 x0 = *(const float4*)(qb + kc * 16 + hi5 * 8);
      float4 x1 = *(const float4*)(qb + kc * 16 + hi5 * 8 + 4);
      bf16x8 f;
      f[0] = (bf16_t)(x0.x * QSCALE_LOG2E); f[1] = (bf16_t)(x0.y * QSCALE_LOG2E);
      f[2] = (bf16_t)(x0.z * QSCALE_LOG2E); f[3] = (bf16_t)(x0.w * QSCALE_LOG2E);
      f[4] = (bf16_t)(x1.x * QSCALE_LOG2E); f[5] = (bf16_t)(x1.y * QSCALE_LOG2E);
      f[6] = (bf16_t)(x1.z * QSCALE_LOG2E); f[7] = (bf16_t)(x1.w * QSCALE_LOG2E);
      qf[kc] = f;
    }
  }

  f32x16 oacc[4];
  #pragma unroll
  for (int i = 0; i < 4; ++i) oacc[i] = (f32x16)(0.f);
  float mreg = -1e30f, lreg = 0.f;

  const int ntiles = (s + qt * 128 + 128 + KVBLK - 1) / KVBLK;
  int cur = 0;
  STAGE(0, 0);
  __syncthreads();

  for (int t = 0; t < ntiles; ++t) {
    const int l0 = t * KVBLK;
    if (t + 1 < ntiles) STAGE(cur ^ 1, t + 1);

    if (l0 <= s + qw + 31) {           // wave has any unmasked element
      // ---- S^T = K · Q : 2 l-subtiles x 8 k-chunks ----
      f32x16 sacc[2];
      __builtin_amdgcn_s_setprio(1);
      #pragma unroll
      for (int sl = 0; sl < 2; ++sl) {
        f32x16 acc = (f32x16)(0.f);
        const int krow = sl * 32 + l5;
        #pragma unroll
        for (int kc = 0; kc < 8; ++kc) {
          bf16x8 kf = *(const bf16x8*)
              &Kl[cur][krow * ND + (((kc * 2 + hi5) ^ (l5 & 7)) * 8)];
          acc = __builtin_amdgcn_mfma_f32_32x32x16_bf16(kf, qf[kc], acc, 0, 0, 0);
        }
        sacc[sl] = acc;
      }
      __builtin_amdgcn_s_setprio(0);
      // ---- ragged-causal mask ----
      if (l0 + 63 > s + qw) {
        const int lim = s + q - l0;
        #pragma unroll
        for (int sl = 0; sl < 2; ++sl)
          #pragma unroll
          for (int rr = 0; rr < 16; ++rr) {
            const int ll = sl * 32 + (rr & 3) + 8 * (rr >> 2) + 4 * hi5;
            if (ll > lim) sacc[sl][rr] = -1e30f;
          }
      }
      // ---- online softmax in log2 domain, defer-max (THR=8) ----
      float pmax = sacc[0][0];
      #pragma unroll
      for (int sl = 0; sl < 2; ++sl)
        #pragma unroll
        for (int rr = 0; rr < 16; ++rr) pmax = fmaxf(pmax, sacc[sl][rr]);
      pmax = fmaxf(pmax, __shfl_xor(pmax, 32, 64));
      if (!__all(pmax - mreg <= 8.f)) {
        const float mnew  = fmaxf(mreg, pmax);
        const float alpha = exp2f(mreg - mnew);
        mreg = mnew;
        lreg *= alpha;
        #pragma unroll
        for (int i = 0; i < 4; ++i) oacc[i] *= alpha;
      }
      float tsum = 0.f;
      #pragma unroll
      for (int sl = 0; sl < 2; ++sl)
        #pragma unroll
        for (int rr = 0; rr < 16; ++rr) {
          const float p = exp2f(sacc[sl][rr] - mreg);
          sacc[sl][rr] = p;
          tsum += p;
        }
      lreg += tsum + __shfl_xor(tsum, 32, 64);

      // ---- pack P rows to bf16 4-run groups: pk[sl][m][dword] ----
      u32 pk[2][4][2];
      #pragma unroll
      for (int sl = 0; sl < 2; ++sl)
        #pragma unroll
        for (int m = 0; m < 4; ++m) {
          pk[sl][m][0] = pack_bf16(sacc[sl][m * 4 + 0], sacc[sl][m * 4 + 1]);
          pk[sl][m][1] = pack_bf16(sacc[sl][m * 4 + 2], sacc[sl][m * 4 + 3]);
        }
      // ---- half-swap exchange -> PV B-frags pb[c] (k = c*16 + hi5*8 + j) ----
      bf16x8 pb[4];
      #pragma unroll
      for (int c = 0; c < 4; ++c) {
        const int slp = c >> 1;
        const u32 k0 = hi5 ? pk[slp][(2 * c + 1) & 3][0] : pk[slp][(2 * c) & 3][0];
        const u32 k1 = hi5 ? pk[slp][(2 * c + 1) & 3][1] : pk[slp][(2 * c) & 3][1];
        const u32 s0 = hi5 ? pk[slp][(2 * c) & 3][0] : pk[slp][(2 * c + 1) & 3][0];
        const u32 s1 = hi5 ? pk[slp][(2 * c) & 3][1] : pk[slp][(2 * c + 1) & 3][1];
        const u32 r0 = (u32)__shfl_xor((int)s0, 32, 64);
        const u32 r1 = (u32)__shfl_xor((int)s1, 32, 64);
        union { u32 w[4]; bf16x8 v; } u;
        u.w[0] = hi5 ? r0 : k0;
        u.w[1] = hi5 ? r1 : k1;
        u.w[2] = hi5 ? k0 : r0;
        u.w[3] = hi5 ? k1 : r1;
        pb[c] = u.v;
      }
      // ---- O^T += V^T · P^T : 4 d-subtiles x 4 k-chunks ----
      __builtin_amdgcn_s_setprio(1);
      #pragma unroll
      for (int ds = 0; ds < 4; ++ds) {
        const int vrow = ds * 32 + l5;
        #pragma unroll
        for (int c = 0; c < 4; ++c) {
          bf16x8 va = *(const bf16x8*)
              &Vl[cur][vrow * KVBLK + (((c * 2 + hi5) ^ (l5 & 7)) * 8)];
          oacc[ds] = __builtin_amdgcn_mfma_f32_32x32x16_bf16(va, pb[c], oacc[ds], 0, 0, 0);
        }
      }
      __builtin_amdgcn_s_setprio(0);
    }
    __syncthreads();
    cur ^= 1;
  }

  // ---- epilogue: normalize, store O (d = ds*32 + 8*rq + 4*hi5 + rr) ----
  const float linv = 1.0f / lreg;
  float* ob = out + ((size_t)((b * NQL + q) * NH + h)) * ND;
  #pragma unroll
  for (int ds = 0; ds < 4; ++ds)
    #pragma unroll
    for (int rq = 0; rq < 4; ++rq) {
      float4 v;
      v.x = oacc[ds][rq * 4 + 0] * linv;
      v.y = oacc[ds][rq * 4 + 1] * linv;
      v.z = oacc[ds][rq * 4 + 2] * linv;
      v.w = oacc[ds][rq * 4 + 3] * linv;
      *(float4*)(ob + ds * 32 + rq * 8 + hi5 * 4) = v;
    }
}

// ---------------------------------------------------------------------------
extern "C" void kernel_launch(void* const* d_in, const int* in_sizes, int n_in,
                              void* d_out, int out_size, void* d_ws, size_t ws_size,
                              hipStream_t stream)
{
  const float* q        = (const float*)d_in[0];
  const float* k        = (const float*)d_in[1];
  const float* v        = (const float*)d_in[2];
  const float* cache_k  = (const float*)d_in[3];
  const float* cache_v  = (const float*)d_in[4];
  const int*   seq_lens = (const int*)d_in[5];

  float* out    = (float*)d_out;
  float* new_ck = out + (size_t)NB * NQL * NH * ND;
  float* new_cv = new_ck + (size_t)NB * NKVH * NL * ND;

  bf16_t* kb = (bf16_t*)d_ws;                                 // 8 MB bf16 K
  bf16_t* vt = kb + (size_t)NB * NKVH * NL * ND;              // 8 MB bf16 V^T

  hipLaunchKernelGGL(update_cache_kernel, dim3(2048), dim3(256), 0, stream,
                     k, v, cache_k, cache_v, seq_lens, new_ck, new_cv, kb);
  hipLaunchKernelGGL(transpose_v_kernel, dim3(NB * NKVH * (NL / 64)), dim3(256), 0, stream,
                     new_cv, vt);
  hipLaunchKernelGGL(attn_kernel, dim3(512), dim3(256), 0, stream,
                     q, kb, vt, seq_lens, out);
}

// Round 5
// 110.170 us; speedup vs baseline: 1.1926x; 1.1926x over previous
//
#include <hip/hip_runtime.h>
#include <hip/hip_bf16.h>
#include <stdint.h>

#define NB 4
#define NQL 1024
#define NL 2048
#define NH 16
#define NKVH 4
#define ND 128
#define KVBLK 64
// (1/sqrt(128)) * log2(e): scores land in log2 domain, softmax uses exp2
#define QSCALE_LOG2E 0.1275174340213733f

typedef __bf16 bf16_t;
typedef __bf16 bf16x4 __attribute__((ext_vector_type(4)));
typedef __bf16 bf16x8 __attribute__((ext_vector_type(8)));
typedef float f32x4 __attribute__((ext_vector_type(4)));
typedef float f32x16 __attribute__((ext_vector_type(16)));
typedef uint32_t u32;
typedef unsigned short u16;

__device__ __forceinline__ void gload_lds16(const void* g, void* l) {
  __builtin_amdgcn_global_load_lds((const __attribute__((address_space(1))) void*)g,
                                   (__attribute__((address_space(3))) void*)l,
                                   16, 0, 0);
}

__device__ __forceinline__ u32 pack_bf16(float a, float b) {
  u32 ua = (u32)__builtin_bit_cast(u16, (bf16_t)a);
  u32 ub = (u32)__builtin_bit_cast(u16, (bf16_t)b);
  return ua | (ub << 16);
}

// ---------------------------------------------------------------------------
// Kernel 1: scatter new k/v into caches -> f32 outputs; also bf16 K copy to ws.
// ---------------------------------------------------------------------------
__global__ __launch_bounds__(256) void update_cache_kernel(
    const float* __restrict__ knew,
    const float* __restrict__ vnew,
    const float* __restrict__ cache_k,
    const float* __restrict__ cache_v,
    const int*   __restrict__ seq_lens,
    float* __restrict__ new_ck,
    float* __restrict__ new_cv,
    bf16_t* __restrict__ kb)
{
  const int n4 = NB * NKVH * NL * ND / 4;
  for (int i = blockIdx.x * blockDim.x + threadIdx.x; i < 2 * n4;
       i += gridDim.x * blockDim.x) {
    const int which = i >= n4;
    const int j   = which ? i - n4 : i;
    const int d4  = j & 31;
    const int l   = (j >> 5) & (NL - 1);
    const int kvh = (j >> 16) & (NKVH - 1);
    const int b   = j >> 18;
    const int s   = seq_lens[b];
    float4 val;
    if (l >= s && l < s + NQL) {
      const float* nsrc = which ? vnew : knew;
      val = *(const float4*)(nsrc + (((size_t)(b * NQL + (l - s))) * NKVH + kvh) * ND + d4 * 4);
    } else {
      const float* csrc = which ? cache_v : cache_k;
      val = *(const float4*)(csrc + (((size_t)(b * NKVH + kvh)) * NL + l) * ND + d4 * 4);
    }
    const size_t coff = (((size_t)(b * NKVH + kvh)) * NL + l) * ND + d4 * 4;
    float* dst = which ? new_cv : new_ck;
    *(float4*)(dst + coff) = val;
    if (!which) {
      bf16x4 kv;
      kv[0] = (bf16_t)val.x; kv[1] = (bf16_t)val.y;
      kv[2] = (bf16_t)val.z; kv[3] = (bf16_t)val.w;
      *(bf16x4*)(kb + coff) = kv;
    }
  }
}

// ---------------------------------------------------------------------------
// Kernel 2: build bf16 V^T [B][KVH][D][L] from updated f32 V cache.
// ---------------------------------------------------------------------------
__global__ __launch_bounds__(256) void transpose_v_kernel(
    const float* __restrict__ new_cv, bf16_t* __restrict__ vt)
{
  __shared__ float T[64][129];
  const int tid = threadIdx.x;
  const int bid = blockIdx.x;        // B*KVH*(NL/64) = 512
  const int lt  = bid & 31;
  const int kvh = (bid >> 5) & (NKVH - 1);
  const int b   = bid >> 7;
  const int l0  = lt * 64;

  const float* src = new_cv + (((size_t)(b * NKVH + kvh)) * NL + l0) * ND;
  #pragma unroll
  for (int j = 0; j < 8; ++j) {
    const int i   = tid + j * 256;
    const int row = i >> 5, c4 = i & 31;
    float4 v = *(const float4*)(src + row * ND + c4 * 4);
    T[row][c4 * 4 + 0] = v.x; T[row][c4 * 4 + 1] = v.y;
    T[row][c4 * 4 + 2] = v.z; T[row][c4 * 4 + 3] = v.w;
  }
  __syncthreads();
  bf16_t* dst = vt + ((size_t)(b * NKVH + kvh)) * ND * NL;
  #pragma unroll
  for (int j = 0; j < 4; ++j) {
    const int c = tid + j * 256;
    const int d = c >> 3, l8 = c & 7;
    bf16x8 o;
    #pragma unroll
    for (int e = 0; e < 8; ++e) o[e] = (bf16_t)T[l8 * 8 + e][d];
    *(bf16x8*)(dst + (size_t)d * NL + l0 + l8 * 8) = o;
  }
}

// ---------------------------------------------------------------------------
// Kernel 3: pipelined flash attention. 512 blocks x 4 waves; wave owns 32 q.
// Schedule invariant: a shared LDS buffer is written ONLY in the phase right
// after its last-reader phase (one barrier between), and read starting the
// phase after the write was issued (barrier drains vmcnt).
//   phase t: barrier; STAGE_K(cur,t+2); STAGE_V(cur^1,t+1);
//            QKT(tile t+1 from Kl[cur^1]); SOFTPV(tile t from Vl[cur]).
// ---------------------------------------------------------------------------
#define STAGE_K(buf, tt) do {                                                \
    const int l0s = (tt) * KVBLK;                                            \
    _Pragma("unroll")                                                        \
    for (int j = 0; j < 4; ++j) {                                            \
      const int ck = tid + j * 256;                                          \
      const int kr = ck >> 4, kc2 = (ck & 15) ^ (kr & 7);                    \
      gload_lds16(kbb + (size_t)(l0s + kr) * ND + kc2 * 8,                   \
                  &Kl[buf][(wave * 64 + j * 256) * 8]);                      \
    }                                                                        \
  } while (0)

#define STAGE_V(buf, tt) do {                                                \
    const int l0s = (tt) * KVBLK;                                            \
    _Pragma("unroll")                                                        \
    for (int j = 0; j < 4; ++j) {                                            \
      const int ck = tid + j * 256;                                          \
      const int vr = ck >> 3, vc2 = (ck & 7) ^ (vr & 7);                     \
      gload_lds16(vtb + (size_t)vr * NL + (l0s + vc2 * 8),                   \
                  &Vl[buf][(wave * 64 + j * 256) * 8]);                      \
    }                                                                        \
  } while (0)

// S^T(tile) = K.Q from Kl[KBI] into SB[2]
#define QKT(SB, KBI) do {                                                    \
    _Pragma("unroll")                                                        \
    for (int sl = 0; sl < 2; ++sl) {                                         \
      f32x16 acc = (f32x16)(0.f);                                            \
      const int krow = sl * 32 + l5;                                         \
      _Pragma("unroll")                                                      \
      for (int kc = 0; kc < 8; ++kc) {                                       \
        bf16x8 kf = *(const bf16x8*)                                         \
            &Kl[KBI][krow * ND + (((kc * 2 + hi5) ^ (l5 & 7)) * 8)];         \
        acc = __builtin_amdgcn_mfma_f32_32x32x16_bf16(kf, qf[kc], acc, 0, 0, 0); \
      }                                                                      \
      SB[sl] = acc;                                                          \
    }                                                                        \
  } while (0)

// mask + online softmax + PV for tile at L0 using SB[2] and Vl[VBI]
#define SOFTPV(SB, VBI, L0) do {                                             \
    if ((L0) + 63 > s + qw) {                                                \
      const int lim = s + q - (L0);                                          \
      _Pragma("unroll")                                                      \
      for (int sl = 0; sl < 2; ++sl)                                         \
        _Pragma("unroll")                                                    \
        for (int rr = 0; rr < 16; ++rr) {                                    \
          const int ll = sl * 32 + (rr & 3) + 8 * (rr >> 2) + 4 * hi5;       \
          if (ll > lim) SB[sl][rr] = -1e30f;                                 \
        }                                                                    \
    }                                                                        \
    float pmax = SB[0][0];                                                   \
    _Pragma("unroll")                                                        \
    for (int sl = 0; sl < 2; ++sl)                                           \
      _Pragma("unroll")                                                      \
      for (int rr = 0; rr < 16; ++rr) pmax = fmaxf(pmax, SB[sl][rr]);        \
    pmax = fmaxf(pmax, __shfl_xor(pmax, 32, 64));                            \
    if (!__all(pmax - mreg <= 8.f)) {                                        \
      const float mnew  = fmaxf(mreg, pmax);                                 \
      const float alpha = exp2f(mreg - mnew);                                \
      mreg = mnew;                                                           \
      lreg *= alpha;                                                         \
      _Pragma("unroll")                                                      \
      for (int i = 0; i < 4; ++i) oacc[i] *= alpha;                          \
    }                                                                        \
    float tsum = 0.f;                                                        \
    _Pragma("unroll")                                                        \
    for (int sl = 0; sl < 2; ++sl)                                           \
      _Pragma("unroll")                                                      \
      for (int rr = 0; rr < 16; ++rr) {                                      \
        const float p = exp2f(SB[sl][rr] - mreg);                            \
        SB[sl][rr] = p;                                                      \
        tsum += p;                                                           \
      }                                                                      \
    lreg += tsum + __shfl_xor(tsum, 32, 64);                                 \
    u32 pk[2][4][2];                                                         \
    _Pragma("unroll")                                                        \
    for (int sl = 0; sl < 2; ++sl)                                           \
      _Pragma("unroll")                                                      \
      for (int m = 0; m < 4; ++m) {                                          \
        pk[sl][m][0] = pack_bf16(SB[sl][m * 4 + 0], SB[sl][m * 4 + 1]);      \
        pk[sl][m][1] = pack_bf16(SB[sl][m * 4 + 2], SB[sl][m * 4 + 3]);      \
      }                                                                      \
    bf16x8 pb[4];                                                            \
    _Pragma("unroll")                                                        \
    for (int c = 0; c < 4; ++c) {                                            \
      const int slp = c >> 1;                                                \
      const u32 k0 = hi5 ? pk[slp][(2 * c + 1) & 3][0] : pk[slp][(2 * c) & 3][0]; \
      const u32 k1 = hi5 ? pk[slp][(2 * c + 1) & 3][1] : pk[slp][(2 * c) & 3][1]; \
      const u32 s0 = hi5 ? pk[slp][(2 * c) & 3][0] : pk[slp][(2 * c + 1) & 3][0]; \
      const u32 s1 = hi5 ? pk[slp][(2 * c) & 3][1] : pk[slp][(2 * c + 1) & 3][1]; \
      const u32 r0 = (u32)__shfl_xor((int)s0, 32, 64);                       \
      const u32 r1 = (u32)__shfl_xor((int)s1, 32, 64);                       \
      union { u32 w[4]; bf16x8 v; } u;                                       \
      u.w[0] = hi5 ? r0 : k0;                                                \
      u.w[1] = hi5 ? r1 : k1;                                                \
      u.w[2] = hi5 ? k0 : r0;                                                \
      u.w[3] = hi5 ? k1 : r1;                                                \
      pb[c] = u.v;                                                           \
    }                                                                        \
    _Pragma("unroll")                                                        \
    for (int ds = 0; ds < 4; ++ds) {                                         \
      const int vrow = ds * 32 + l5;                                         \
      _Pragma("unroll")                                                      \
      for (int c = 0; c < 4; ++c) {                                          \
        bf16x8 va = *(const bf16x8*)                                         \
            &Vl[VBI][vrow * KVBLK + (((c * 2 + hi5) ^ (l5 & 7)) * 8)];       \
        oacc[ds] = __builtin_amdgcn_mfma_f32_32x32x16_bf16(va, pb[c], oacc[ds], 0, 0, 0); \
      }                                                                      \
    }                                                                        \
  } while (0)

__global__ __launch_bounds__(256, 2) void attn_kernel(
    const float* __restrict__ qin, const bf16_t* __restrict__ kb,
    const bf16_t* __restrict__ vt, const int* __restrict__ seq_lens,
    float* __restrict__ out)
{
  __shared__ bf16_t Kl[2][KVBLK * ND];   // 32 KB (XOR-swizzled rows of 256B)
  __shared__ bf16_t Vl[2][ND * KVBLK];   // 32 KB (XOR-swizzled rows of 128B)

  const int tid  = threadIdx.x;
  const int wave = tid >> 6, lane = tid & 63;
  const int l5   = lane & 31;            // q column within wave
  const int hi5  = lane >> 5;

  // Round-2 mapping: bid and bid+256 share (b, kvh) -> co-resident blocks
  // stream the same K/V panel (L2 reuse); complementary qt balances pairs.
  const int bid  = blockIdx.x;
  const int half = bid >> 8, r = bid & 255;
  const int b    = r >> 6;
  const int h    = (r >> 2) & (NH - 1);
  const int qt   = half ? (7 - ((r & 3) << 1)) : ((r & 3) << 1);
  const int kvh  = h >> 2;
  const int s    = seq_lens[b];
  const int qw   = qt * 128 + wave * 32;
  const int q    = qw + l5;

  const bf16_t* kbb = kb + ((size_t)(b * NKVH + kvh)) * NL * ND;
  const bf16_t* vtb = vt + ((size_t)(b * NKVH + kvh)) * ND * NL;

  // Q fragments (B operand of S^T): qf[kc][j] = Q[q][kc*16 + hi5*8 + j]
  bf16x8 qf[8];
  {
    const float* qb = qin + ((size_t)((b * NQL + q) * NH + h)) * ND;
    #pragma unroll
    for (int kc = 0; kc < 8; ++kc) {
      float4 x0 = *(const float4*)(qb + kc * 16 + hi5 * 8);
      float4 x1 = *(const float4*)(qb + kc * 16 + hi5 * 8 + 4);
      bf16x8 f;
      f[0] = (bf16_t)(x0.x * QSCALE_LOG2E); f[1] = (bf16_t)(x0.y * QSCALE_LOG2E);
      f[2] = (bf16_t)(x0.z * QSCALE_LOG2E); f[3] = (bf16_t)(x0.w * QSCALE_LOG2E);
      f[4] = (bf16_t)(x1.x * QSCALE_LOG2E); f[5] = (bf16_t)(x1.y * QSCALE_LOG2E);
      f[6] = (bf16_t)(x1.z * QSCALE_LOG2E); f[7] = (bf16_t)(x1.w * QSCALE_LOG2E);
      qf[kc] = f;
    }
  }

  f32x16 oacc[4];
  #pragma unroll
  for (int i = 0; i < 4; ++i) oacc[i] = (f32x16)(0.f);
  float mreg = -1e30f, lreg = 0.f;

  const int ntiles = (s + qt * 128 + 128 + KVBLK - 1) / KVBLK;  // >= 2 always

  // ---- prologue ("phase -1"): stage K0, V0, K1; compute QK(0) ----
  STAGE_K(0, 0);
  STAGE_V(0, 0);
  STAGE_K(1, 1);
  __syncthreads();

  f32x16 sA[2], sB[2];
  QKT(sA, 0);

  // ---- main loop, 2 phases per trip, all buffer indices static ----
  for (int t = 0; ; t += 2) {
    // --- phase t (cur=0): tile t uses Kl[0]/Vl[0] ---
    __syncthreads();                       // drains K(t+1)->Kl[1], V(t)->Vl[0]
    if (t + 2 < ntiles) STAGE_K(0, t + 2); // Kl[0] last read phase t-1 (QKT)
    if (t + 1 < ntiles) STAGE_V(1, t + 1); // Vl[1] last read phase t-1 (PV)
    const bool gB = (t + 1 < ntiles) && ((t + 1) * KVBLK <= s + qw + 31);
    if (gB) QKT(sB, 1);
    if (t * KVBLK <= s + qw + 31) SOFTPV(sA, 0, t * KVBLK);
    if (t + 1 >= ntiles) break;

    // --- phase t+1 (cur=1): tile t+1 uses Kl[1]/Vl[1] ---
    __syncthreads();                       // drains K(t+2)->Kl[0], V(t+1)->Vl[1]
    if (t + 3 < ntiles) STAGE_K(1, t + 3); // Kl[1] last read phase t (QKT)
    if (t + 2 < ntiles) STAGE_V(0, t + 2); // Vl[0] last read phase t (PV)
    const bool gA = (t + 2 < ntiles) && ((t + 2) * KVBLK <= s + qw + 31);
    if (gA) QKT(sA, 0);
    if ((t + 1) * KVBLK <= s + qw + 31) SOFTPV(sB, 1, (t + 1) * KVBLK);
    if (t + 2 >= ntiles) break;
  }

  // ---- epilogue: normalize, store O (d = ds*32 + 8*rq + 4*hi5 + rr) ----
  const float linv = 1.0f / lreg;
  float* ob = out + ((size_t)((b * NQL + q) * NH + h)) * ND;
  #pragma unroll
  for (int ds = 0; ds < 4; ++ds)
    #pragma unroll
    for (int rq = 0; rq < 4; ++rq) {
      float4 v;
      v.x = oacc[ds][rq * 4 + 0] * linv;
      v.y = oacc[ds][rq * 4 + 1] * linv;
      v.z = oacc[ds][rq * 4 + 2] * linv;
      v.w = oacc[ds][rq * 4 + 3] * linv;
      *(float4*)(ob + ds * 32 + rq * 8 + hi5 * 4) = v;
    }
}

// ---------------------------------------------------------------------------
extern "C" void kernel_launch(void* const* d_in, const int* in_sizes, int n_in,
                              void* d_out, int out_size, void* d_ws, size_t ws_size,
                              hipStream_t stream)
{
  const float* q        = (const float*)d_in[0];
  const float* k        = (const float*)d_in[1];
  const float* v        = (const float*)d_in[2];
  const float* cache_k  = (const float*)d_in[3];
  const float* cache_v  = (const float*)d_in[4];
  const int*   seq_lens = (const int*)d_in[5];

  float* out    = (float*)d_out;
  float* new_ck = out + (size_t)NB * NQL * NH * ND;
  float* new_cv = new_ck + (size_t)NB * NKVH * NL * ND;

  bf16_t* kb = (bf16_t*)d_ws;                                 // 8 MB bf16 K
  bf16_t* vt = kb + (size_t)NB * NKVH * NL * ND;              // 8 MB bf16 V^T

  hipLaunchKernelGGL(update_cache_kernel, dim3(2048), dim3(256), 0, stream,
                     k, v, cache_k, cache_v, seq_lens, new_ck, new_cv, kb);
  hipLaunchKernelGGL(transpose_v_kernel, dim3(NB * NKVH * (NL / 64)), dim3(256), 0, stream,
                     new_cv, vt);
  hipLaunchKernelGGL(attn_kernel, dim3(512), dim3(256), 0, stream,
                     q, kb, vt, seq_lens, out);
}